// Round 8
// baseline (684.411 us; speedup 1.0000x reference)
//
#include <hip/hip_runtime.h>

#define HH 80
#define WW 80
#define NPIX 6400
#define PW 82
#define NPP (PW*PW)        // 6724 padded pixels
#define CFE 64
#define CMA 3
#define KF 576
#define GUARD 1024
#define NREG 8

#define PA 1024            // S0 row window per block (incl. 84+84 halo)
#define POUT 856           // output rows per block
#define BW 1056            // B row window = PA + 32

typedef unsigned long long u64;
typedef unsigned int u32;

__device__ __forceinline__ void gload4(const float* g, float* l) {
    __builtin_amdgcn_global_load_lds((const __attribute__((address_space(1))) void*)g,
                                     (__attribute__((address_space(3))) void*)l, 4, 0, 0);
}
__device__ __forceinline__ float4 ld4(const float* p) { return *(const float4*)p; }

// ---------------------------------------------------------------------------
// per-pixel channel sum-of-squares (style side only), real grid
// ---------------------------------------------------------------------------
__global__ __launch_bounds__(256)
void pixsq_kernel(const float* __restrict__ sf, const float* __restrict__ sm,
                  float* __restrict__ psf, float* __restrict__ psm) {
    int g = blockIdx.x * 256 + threadIdx.x;
    if (g >= 2 * NPIX) return;
    int b = g / NPIX, m = g - b * NPIX;
    const float* p = sf + (size_t)b * CFE * NPIX + m;
    float a = 0.f;
    #pragma unroll 8
    for (int c = 0; c < CFE; ++c) { float v = p[c * NPIX]; a = fmaf(v, v, a); }
    const float* q = sm + (size_t)b * CMA * NPIX + m;
    float am = 0.f;
    #pragma unroll
    for (int c = 0; c < CMA; ++c) { float v = q[c * NPIX]; am = fmaf(v, v, am); }
    psf[g] = a; psm[g] = am;
}

// 9-tap masked patch-norms -> combined reciprocal, written to PADDED layout.
// rn2p[b][mp] = 1/(||f||*||m||) at padded index mp; 0 elsewhere (pre-zeroed).
__global__ __launch_bounds__(256)
void rn2_kernel(const float* __restrict__ psf, const float* __restrict__ psm,
                float* __restrict__ rn2p) {
    int g = blockIdx.x * 256 + threadIdx.x;
    if (g >= 2 * NPIX) return;
    int b = g / NPIX, m = g - b * NPIX;
    int mh = m / WW, mw = m - mh * WW;
    float sF = 0.f, sM = 0.f;
    #pragma unroll
    for (int di = -1; di <= 1; ++di) {
        if ((unsigned)(mh + di) >= HH) continue;
        #pragma unroll
        for (int dj = -1; dj <= 1; ++dj) {
            if ((unsigned)(mw + dj) >= WW) continue;
            int mm = m + di * WW + dj;
            sF += psf[b * NPIX + mm];
            sM += psm[b * NPIX + mm];
        }
    }
    float rf = 1.f / fmaxf(sqrtf(sF), 1e-12f);
    float rm = 1.f / fmaxf(sqrtf(sM), 1e-12f);
    rn2p[(size_t)b * NPP + (mh + 1) * PW + (mw + 1)] = rf * rm;
}

// ---------------------------------------------------------------------------
// Build zero-padded 82x82 copies (borders pre-zeroed by the memset).
// ---------------------------------------------------------------------------
__global__ __launch_bounds__(256)
void pad_kernel(const float* __restrict__ cf, const float* __restrict__ sf,
                const float* __restrict__ cm, const float* __restrict__ sm,
                float* __restrict__ cfp, float* __restrict__ sfp,
                float* __restrict__ cmp, float* __restrict__ smp) {
    int gid = blockIdx.x * 256 + threadIdx.x;
    if (gid >= 2 * 2 * 67 * NPIX) return;
    int pix = gid % NPIX; int t = gid / NPIX;
    int c = t % 67; t /= 67;
    int b = t & 1; int which = t >> 1;
    int h = pix / WW, w = pix - h * WW;
    int qq = (h + 1) * PW + (w + 1);
    if (which == 0) {
        if (c < 64) cfp[((size_t)b * CFE + c) * NPP + qq] = cf[((size_t)b * CFE + c) * NPIX + pix];
        else        cmp[((size_t)b * CMA + (c - 64)) * NPP + qq] = cm[((size_t)b * CMA + (c - 64)) * NPIX + pix];
    } else {
        if (c < 64) sfp[((size_t)b * CFE + c) * NPP + qq] = sf[((size_t)b * CFE + c) * NPIX + pix];
        else        smp[((size_t)b * CMA + (c - 64)) * NPP + qq] = sm[((size_t)b * CMA + (c - 64)) * NPIX + pix];
    }
}

// ---------------------------------------------------------------------------
// Fused: correlation GEMM (diagonal coords) + maskless 9-tap stencil + score
// + argmax. 512 threads, acc[4][16], XOR-swizzled S0 buffer.
// ---------------------------------------------------------------------------
__global__ __launch_bounds__(512, 2)
void fuse_kernel(const float* __restrict__ cfp, const float* __restrict__ sfp,
                 const float* __restrict__ cmp, const float* __restrict__ smp,
                 const float* __restrict__ rn2p, u64* __restrict__ pbest) {
    const int pt = blockIdx.y;
    const int b  = blockIdx.z;
    const int pstart = 83 + POUT * pt;
    const int pend   = min(pstart + POUT, 6641);
    const int pbase  = pstart - 84;
    const int dte0   = (6644 - pend) >> 5;       // first useful 32-d tile
    const int dtemax = (13200 - pstart) >> 5;    // last useful 32-d tile
    const int dte = dte0 + blockIdx.x;
    if (dte > dtemax) return;
    const int d0 = -6560 + 32 * dte;

    __shared__ float pool[PA * 36];              // 147456 B

    const int tid = threadIdx.x;
    const int tp = tid & 255;                    // row group (4 rows)
    const int tg = tid >> 8;                     // d half (16 cols)
    const int wb = tid & 448;                    // wave-uniform LDS float offset
    const int swz = (tp & 7) << 2;               // this thread's s0write swizzle

    const float* cfb = cfp + (size_t)b * CFE * NPP + pbase;
    const float* sfb = sfp + (size_t)b * CFE * NPP + pbase + d0;
    const float* cmb = cmp + (size_t)b * CMA * NPP + pbase;
    const float* smb = smp + (size_t)b * CMA * NPP + pbase + d0;

    float acc[4][16];
    float pdF[2][32], pdM[2][32];

    auto zacc = [&]() {
        #pragma unroll
        for (int k = 0; k < 4; ++k)
            #pragma unroll
            for (int j = 0; j < 16; ++j) acc[k][j] = 0.f;
    };

    // stage one 8-channel chunk: A rows PA, B rows BW
    auto stageF = [&](int q, int buf) {
        float* Ab = pool + buf * 16640;
        float* Bb = Ab + 8 * PA;
        const float* As = cfb + (size_t)(q * 8) * NPP;
        const float* Bs = sfb + (size_t)(q * 8) * NPP;
        #pragma unroll
        for (int cc = 0; cc < 8; ++cc) {
            gload4(As + cc * NPP + tid,       Ab + cc * PA + wb);
            gload4(As + cc * NPP + 512 + tid, Ab + cc * PA + 512 + wb);
            gload4(Bs + cc * NPP + tid,       Bb + cc * BW + wb);
            gload4(Bs + cc * NPP + 512 + tid, Bb + cc * BW + 512 + wb);
            if (tid < 32) gload4(Bs + cc * NPP + 1024 + tid, Bb + cc * BW + 1024);
        }
    };

    // one channel: acc[k][j] += A[4tp+k] * B[4tp+k + 16tg+j]
    auto gemmc = [&](const float* Ab, const float* Bb) {
        const float* Ar = Ab + 4 * tp;
        const float* Br = Bb + 4 * tp + 16 * tg;
        float a[4], bb[20];
        *(float4*)a         = ld4(Ar);
        *(float4*)bb        = ld4(Br);
        *(float4*)(bb + 4)  = ld4(Br + 4);
        *(float4*)(bb + 8)  = ld4(Br + 8);
        *(float4*)(bb + 12) = ld4(Br + 12);
        *(float4*)(bb + 16) = ld4(Br + 16);
        #pragma unroll
        for (int k = 0; k < 4; ++k)
            #pragma unroll
            for (int j = 0; j < 16; ++j)
                acc[k][j] = fmaf(a[k], bb[k + j], acc[k][j]);
    };

    // acc -> S0 LDS [PA rows][32 d], row stride 36, XOR-swizzled columns
    auto s0write = [&]() {
        #pragma unroll
        for (int k = 0; k < 4; ++k) {
            float* dr = pool + (4 * tp + k) * 36;
            #pragma unroll
            for (int g = 0; g < 4; ++g) {
                *(float4*)(dr + ((16 * tg + 4 * g) ^ swz)) =
                    make_float4(acc[k][4 * g], acc[k][4 * g + 1],
                                acc[k][4 * g + 2], acc[k][4 * g + 3]);
            }
        }
    };

    // maskless 9-tap stencil along p; thread owns rows {tid, tid+512}
    auto tapsrun = [&](float (&pd)[2][32]) {
        #pragma unroll
        for (int s = 0; s < 2; ++s) {
            const int row = tid + 512 * s;
            if (row < 84 || row >= 84 + POUT) continue;
            #pragma unroll
            for (int j4 = 0; j4 < 8; ++j4) {
                float4 v = make_float4(0.f, 0.f, 0.f, 0.f);
                #pragma unroll
                for (int t9 = 0; t9 < 9; ++t9) {
                    static const int dlt[9] = {-83, -82, -81, -1, 0, 1, 81, 82, 83};
                    const int rr = row + dlt[t9];
                    const int sw = ((rr >> 2) & 7) << 2;
                    float4 t = ld4(pool + rr * 36 + ((4 * j4) ^ sw));
                    v.x += t.x; v.y += t.y; v.z += t.z; v.w += t.w;
                }
                pd[s][4 * j4 + 0] = v.x; pd[s][4 * j4 + 1] = v.y;
                pd[s][4 * j4 + 2] = v.z; pd[s][4 * j4 + 3] = v.w;
            }
        }
    };

    // ---- feature correlation: 8 chunks of 8 channels, double-buffered
    zacc();
    stageF(0, 0);
    __syncthreads();
    int buf = 0;
    #pragma unroll 1
    for (int q = 0; q < 8; ++q) {
        if (q < 7) stageF(q + 1, buf ^ 1);
        const float* Ab = pool + buf * 16640;
        const float* Bb = Ab + 8 * PA;
        #pragma unroll 2
        for (int cc = 0; cc < 8; ++cc)
            gemmc(Ab + cc * PA, Bb + cc * BW);
        __syncthreads();
        buf ^= 1;
    }
    s0write();
    __syncthreads();
    tapsrun(pdF);
    __syncthreads();

    // ---- mask correlation: 3 channels, single stage
    #pragma unroll
    for (int cc = 0; cc < 3; ++cc) {
        gload4(cmb + cc * NPP + tid,       pool + cc * PA + wb);
        gload4(cmb + cc * NPP + 512 + tid, pool + cc * PA + 512 + wb);
        gload4(smb + cc * NPP + tid,       pool + 3 * PA + cc * BW + wb);
        gload4(smb + cc * NPP + 512 + tid, pool + 3 * PA + cc * BW + 512 + wb);
        if (tid < 32) gload4(smb + cc * NPP + 1024 + tid, pool + 3 * PA + cc * BW + 1024);
    }
    __syncthreads();
    zacc();
    #pragma unroll
    for (int cc = 0; cc < 3; ++cc)
        gemmc(pool + cc * PA, pool + 3 * PA + cc * BW);
    __syncthreads();
    s0write();
    __syncthreads();
    tapsrun(pdM);

    // ---- score + argmax (padded-rn2 validity, read-filtered atomicMax)
    const float* rb = rn2p + (size_t)b * NPP;
    u64* pb = pbest + ((size_t)(dte & (NREG - 1)) * 2 + b) * NPIX;
    #pragma unroll
    for (int s = 0; s < 2; ++s) {
        const int row = tid + 512 * s;
        const int p = pbase + row;
        if (row < 84 || p >= pend) continue;
        int ph = p / PW, pw2 = p - ph * PW;
        if (ph < 1 || ph > 80 || pw2 < 1 || pw2 > 80) continue;
        int n_real = (ph - 1) * 80 + (pw2 - 1);
        u64 key = 0;
        #pragma unroll
        for (int j = 0; j < 32; ++j) {
            int mp = p + d0 + j;
            if ((unsigned)mp >= (unsigned)NPP) continue;
            float r2 = rb[mp];
            if (r2 == 0.f) continue;                   // pad/border -> invalid m
            float sc = pdF[s][j] * pdM[s][j] * r2;
            sc += 0.f;                                 // -0 -> +0
            u32 u = __float_as_uint(sc);
            u ^= (u >> 31) ? 0xFFFFFFFFu : 0x80000000u;
            u64 k2 = ((u64)u << 32) | (u32)~(u32)mp;   // mp monotone with m_real
            if (k2 > key) key = k2;
        }
        if (key) {
            u64 cur = pb[n_real];                      // monotone -> safe filter
            if (key > cur) atomicMax(&pb[n_real], key);
        }
    }
}

// ---------------------------------------------------------------------------
// Reduce the NREG region keys + gather the winning style patch per n.
// ---------------------------------------------------------------------------
__global__ __launch_bounds__(64)
void gather_kernel(const float* __restrict__ sf, const u64* __restrict__ pbest,
                   float* __restrict__ out) {
    int n = blockIdx.x, b = blockIdx.y;
    int lane = threadIdx.x;

    u64 key = 0;
    #pragma unroll
    for (int r = 0; r < NREG; ++r) {
        u64 k = pbest[((size_t)r * 2 + b) * NPIX + n];
        if (k > key) key = k;
    }
    int mp = (int)(~(u32)key);
    int m = 0;
    if ((unsigned)mp < (unsigned)NPP) {
        int ph = mp / PW, pw = mp - ph * PW;
        if (ph >= 1 && ph <= 80 && pw >= 1 && pw <= 80)
            m = (ph - 1) * 80 + (pw - 1);
    }
    int mh = m / WW, mw = m - mh * WW;
    const float* sfb = sf + (size_t)b * CFE * NPIX;
    float* ob = out + ((size_t)b * NPIX + n) * (size_t)KF;
    #pragma unroll
    for (int e = lane; e < KF; e += 64) {
        int c = e / 9, pos = e - c * 9;
        int di = pos / 3 - 1, dj = pos - (pos / 3) * 3 - 1;
        int h = mh + di, w = mw + dj;
        ob[e] = ((unsigned)h < HH && (unsigned)w < WW) ? sfb[c * NPIX + h * WW + w] : 0.f;
    }
}

// ---------------------------------------------------------------------------
extern "C" void kernel_launch(void* const* d_in, const int* in_sizes, int n_in,
                              void* d_out, int out_size, void* d_ws, size_t ws_size,
                              hipStream_t stream) {
    const float* cf = (const float*)d_in[0];
    const float* sf = (const float*)d_in[1];
    const float* cm = (const float*)d_in[2];
    const float* sm = (const float*)d_in[3];
    float* out = (float*)d_out;

    // ws layout (floats)
    float* psf = (float*)d_ws;                          // 2*NPIX
    float* psm = psf + 2 * NPIX;                        // 2*NPIX
    u64*  pbest = (u64*)(psm + 2 * NPIX);               // NREG*2*NPIX u64
    float* rn2p = (float*)(pbest + (size_t)NREG * 2 * NPIX);  // 2*NPP
    float* padreg = rn2p + 2 * NPP;                     // GUARD
    float* cfp = padreg + GUARD;                        // 2*64*NPP
    float* sfp = cfp + (size_t)2 * CFE * NPP + GUARD;   // 2*64*NPP
    float* cmp = sfp + (size_t)2 * CFE * NPP + GUARD;   // 2*3*NPP
    float* smp = cmp + (size_t)2 * CMA * NPP + GUARD;   // 2*3*NPP (+ trailing GUARD)

    // zero pbest + rn2p + all padded arrays + guards in one contiguous shot
    size_t zero_bytes = (size_t)NREG * 2 * NPIX * 8 +
        ((size_t)2 * NPP + (size_t)5 * GUARD +
         (size_t)4 * CFE * NPP + (size_t)4 * CMA * NPP) * 4;
    hipMemsetAsync(pbest, 0, zero_bytes, stream);

    pad_kernel<<<(2 * 2 * 67 * NPIX + 255) / 256, 256, 0, stream>>>(
        cf, sf, cm, sm, cfp, sfp, cmp, smp);
    pixsq_kernel<<<(2 * NPIX + 255) / 256, 256, 0, stream>>>(sf, sm, psf, psm);
    rn2_kernel  <<<(2 * NPIX + 255) / 256, 256, 0, stream>>>(psf, psm, rn2p);

    fuse_kernel<<<dim3(232, 8, 2), 512, 0, stream>>>(cfp, sfp, cmp, smp, rn2p, pbest);

    gather_kernel<<<dim3(NPIX, 2), 64, 0, stream>>>(sf, pbest, out);
}